// Round 8
// baseline (475.891 us; speedup 1.0000x reference)
//
#include <hip/hip_runtime.h>
#include <math.h>

#define N   2048
#define NT  256
#define V   8

// stable logaddexp (fallback kernel only)
__device__ __forceinline__ float lae(float a, float b) {
    float m  = fmaxf(a, b);
    float mn = fminf(a, b);
    return m + log1pf(expf(mn - m));
}

// exact integer block weight: sum_{j=h}^{e} (N-j)  (< 2^22, exact in fp32)
__device__ __forceinline__ int wsum(int h, int e) {
    return (((N - h) + (N - e)) * (e - h + 1)) >> 1;
}

// padded LDS index for element j: lane-row j>>5 padded to 33 floats
__device__ __forceinline__ int eidx(int j) { return (j >> 5) * 33 + (j & 31); }

// float -> u32 key ascending in theta; we sort ascending on d = ~asc  (desc theta)
__device__ __forceinline__ unsigned desc_key(float t) {
    unsigned u = __float_as_uint(t);
    unsigned a = (u & 0x80000000u) ? ~u : (u ^ 0x80000000u);
    return ~a;
}
__device__ __forceinline__ float decode_key(unsigned d) {
    unsigned a = ~d;
    unsigned u = (a & 0x80000000u) ? (a ^ 0x80000000u) : ~a;
    return __uint_as_float(u);
}

// ---- register bitonic helpers (u32) ---------------------------------------
__device__ __forceinline__ void ceu(unsigned &a, unsigned &b, bool up) {
    unsigned mn = (a < b) ? a : b;
    unsigned mx = (a < b) ? b : a;
    a = up ? mn : mx;
    b = up ? mx : mn;
}

__device__ __forceinline__ void merge8(unsigned* r, bool up) {
    ceu(r[0], r[4], up); ceu(r[1], r[5], up); ceu(r[2], r[6], up); ceu(r[3], r[7], up);
    ceu(r[0], r[2], up); ceu(r[1], r[3], up); ceu(r[4], r[6], up); ceu(r[5], r[7], up);
    ceu(r[0], r[1], up); ceu(r[2], r[3], up); ceu(r[4], r[5], up); ceu(r[6], r[7], up);
}

__device__ __forceinline__ void shfl_ce(unsigned* r, int d, bool keepMin) {
    #pragma unroll
    for (int q = 0; q < V; ++q) {
        unsigned p = __shfl_xor(r[q], d, 64);
        bool lt = r[q] < p;
        r[q] = (lt == keepMin) ? r[q] : p;   // keepMin? min : max
    }
}

// ============================================================================
// Kernel 1: registerized per-row bitonic sort of u32 keys (NO payload).
// V=8/thread; jj<=4 in regs, 8<=jj<=256 via __shfl_xor (1 bpermute each),
// jj in {512,1024} via padded LDS (tid*9+q, gcd(9,32)=1 -> conflict-free).
// Writes theta_sorted (descending) row-major.
// ============================================================================
__global__ void __launch_bounds__(NT)
sort_kernel(const float* __restrict__ x1, const float* __restrict__ x2,
            int nrows, float* __restrict__ ts)
{
    __shared__ unsigned s_kv[NT * 9];   // 9216 B, padded

    const int rid = blockIdx.x;
    const int tid = threadIdx.x;
    const float* __restrict__ x = (rid < nrows) ? x1 : x2;
    const size_t base = (size_t)(rid < nrows ? rid : rid - nrows) * N;

    const float4* __restrict__ xv = (const float4*)(x + base + tid * V);
    float4 a0 = xv[0], a1 = xv[1];
    float th[V] = {a0.x, a0.y, a0.z, a0.w, a1.x, a1.y, a1.z, a1.w};
    unsigned r[V];
    #pragma unroll
    for (int q = 0; q < V; ++q) r[q] = desc_key(th[q] * 10.0f);

    // ---- k=2, k=4 local stages ----
    ceu(r[0], r[1], true);  ceu(r[2], r[3], false);
    ceu(r[4], r[5], true);  ceu(r[6], r[7], false);
    ceu(r[0], r[2], true);  ceu(r[1], r[3], true);
    ceu(r[4], r[6], false); ceu(r[5], r[7], false);
    ceu(r[0], r[1], true);  ceu(r[2], r[3], true);
    ceu(r[4], r[5], false); ceu(r[6], r[7], false);
    // ---- k=8 ----
    merge8(r, (tid & 1) == 0);

    // ---- k=16 .. 2048 ----
    #pragma unroll
    for (int kk = 4; kk <= 11; ++kk) {
        const int k  = 1 << kk;
        const bool up = ((tid & (k >> 3)) == 0);
        #pragma unroll
        for (int jb = kk - 1; jb >= 3; --jb) {
            const int jj = 1 << jb;
            const int d  = jj >> 3;
            if (d >= 64) {
                // cross-wave: padded LDS exchange
                __syncthreads();
                #pragma unroll
                for (int q = 0; q < V; ++q) s_kv[tid * 9 + q] = r[q];
                __syncthreads();
                const bool keepMin = (up == ((tid & d) == 0));
                const int ptid = tid ^ d;
                #pragma unroll
                for (int q = 0; q < V; ++q) {
                    unsigned p = s_kv[ptid * 9 + q];
                    bool lt = r[q] < p;
                    r[q] = (lt == keepMin) ? r[q] : p;
                }
            } else {
                shfl_ce(r, d, up == ((tid & d) == 0));
            }
        }
        merge8(r, up);
    }

    // ---- decode + store theta_sorted (coalesced float4 x2) ----
    float e[V];
    #pragma unroll
    for (int q = 0; q < V; ++q) e[q] = decode_key(r[q]);
    float* __restrict__ so = ts + (size_t)rid * N + tid * V;
    ((float4*)so)[0] = make_float4(e[0], e[1], e[2], e[3]);
    ((float4*)so)[1] = make_float4(e[4], e[5], e[6], e[7]);
}

// next block head after (lane, d) within lanes [.., bEnd); bEnd*32 if none
__device__ __forceinline__ int next_head(const unsigned short* stH,
                                         const unsigned char* sBeg,
                                         const unsigned char* sEnd,
                                         int lane, int d, int bEnd)
{
    if (d + 1 < (int)sEnd[lane]) return stH[(d + 1) * 64 + lane];
    for (int l = lane + 1; l < bEnd; ++l)
        if (sBeg[l] != sEnd[l]) return stH[(int)sBeg[l] * 64 + l];
    return bEnd << 5;
}

// ============================================================================
// Kernel 2: wave-parallel PAV. One wave per row. (structure validated R6/R7)
// Reads theta_sorted; E = exp(theta) computed on ingest; writes r_sorted.
// ============================================================================
__global__ void __launch_bounds__(64)
pav_wave_kernel(const float* __restrict__ ts, float* __restrict__ rs)
{
    __shared__ float          sE[64 * 33];       // 8448 B padded theta -> r
    __shared__ float          stY[32 * 64];      // 8192 B  [d][lane]
    __shared__ unsigned short stH[32 * 64];      // 4096 B  [d][lane]
    __shared__ unsigned char  sBeg[64], sEnd[64];

    const int rid = blockIdx.x;
    const int t   = threadIdx.x;
    const float* __restrict__ trow = ts + (size_t)rid * N;

    for (int j = t; j < N; j += 64) sE[eidx(j)] = trow[j];
    __syncthreads();

    // ---- phase 1: per-lane stack PAV on segment [32t, 32t+32) ----
    {
        int   sp = 0;
        float t0Y = 0.f, t1Y = 0.f;
        int   t0h = 0,   t1h = 0;
        const int base = t << 5;
        for (int k = 0; k < 32; ++k) {
            const int j = base + k;
            float cY = __expf(sE[t * 33 + k]);
            int   ch = j;
            while (sp > 0) {
                float cW = (float)wsum(ch, j);
                float tW = (float)wsum(t0h, ch - 1);
                if (t0Y * cW > cY * tW) break;     // strictly decreasing: stop
                cY += t0Y; ch = t0h;               // pool top into current
                --sp;
                t0Y = t1Y; t0h = t1h;
                if (sp > 1) { t1Y = stY[(sp - 2) * 64 + t]; t1h = stH[(sp - 2) * 64 + t]; }
            }
            stY[sp * 64 + t] = cY;
            stH[sp * 64 + t] = (unsigned short)ch;
            t1Y = t0Y; t1h = t0h;
            t0Y = cY;  t0h = ch;
            ++sp;
        }
        sBeg[t] = 0; sEnd[t] = (unsigned char)sp;
    }
    __syncthreads();

    // ---- phase 2: merge tree (6 levels) ----
    for (int lev = 0; lev < 6; ++lev) {
        const int g = 1 << lev;
        if ((t & (2 * g - 1)) == 0) {
            const int a = t, mid = t + g, b = t + 2 * g;
            int l0 = mid - 1;                       // last nonempty lane of G0
            while (l0 >= a && sBeg[l0] == sEnd[l0]) --l0;
            int l1 = mid;                           // first nonempty lane of G1
            while (l1 < b && sBeg[l1] == sEnd[l1]) ++l1;
            if (l0 >= a && l1 < b) {
                int   d0 = (int)sEnd[l0] - 1;
                float tY = stY[d0 * 64 + l0];
                int   th = stH[d0 * 64 + l0];
                int   te = (mid << 5) - 1;          // G0's last block end
                int   d1 = (int)sBeg[l1];
                float cY = stY[d1 * 64 + l1];
                int   ch = stH[d1 * 64 + l1];
                int   ce = next_head(stH, sBeg, sEnd, l1, d1, b) - 1;
                if (!(tY * (float)wsum(ch, ce) > cY * (float)wsum(th, te))) {
                    sBeg[l1] = (unsigned char)(d1 + 1);   // consume G1 front
                    for (;;) {
                        if (l0 >= a &&
                            !(tY * (float)wsum(ch, ce) > cY * (float)wsum(th, te))) {
                            // pool left: cur absorbs G0 top [th, ch-1]
                            cY += tY;
                            ch  = th;
                            sEnd[l0] = (unsigned char)((int)sEnd[l0] - 1);
                            if (sBeg[l0] == sEnd[l0]) {
                                do { --l0; } while (l0 >= a && sBeg[l0] == sEnd[l0]);
                            }
                            if (l0 >= a) {
                                int dd = (int)sEnd[l0] - 1;
                                tY = stY[dd * 64 + l0];
                                te = th - 1;        // new top's end = absorbed head - 1
                                th = stH[dd * 64 + l0];
                            }
                            continue;
                        }
                        // try pool right: next G1 block
                        while (l1 < b && sBeg[l1] == sEnd[l1]) ++l1;
                        if (l1 < b) {
                            int   dn = (int)sBeg[l1];
                            float nY = stY[dn * 64 + l1];
                            int   nh = stH[dn * 64 + l1];
                            int   ne = next_head(stH, sBeg, sEnd, l1, dn, b) - 1;
                            if (!(cY * (float)wsum(nh, ne) > nY * (float)wsum(ch, ce))) {
                                cY += nY; ce = ne;          // absorb next
                                sBeg[l1] = (unsigned char)(dn + 1);
                                continue;
                            }
                        }
                        break;
                    }
                    // push cur back at its head's lane
                    int lh = ch >> 5;
                    if (ch >= (mid << 5)) {          // head in G1 -> front push
                        int nb = (int)sBeg[lh] - 1;
                        sBeg[lh] = (unsigned char)nb;
                        stY[nb * 64 + lh] = cY;
                        stH[nb * 64 + lh] = (unsigned short)ch;
                    } else {                          // head in G0 -> tail push
                        int nb2 = (int)sEnd[lh];
                        stY[nb2 * 64 + lh] = cY;
                        stH[nb2 * 64 + lh] = (unsigned short)ch;
                        sEnd[lh] = (unsigned char)(nb2 + 1);
                    }
                }
            }
        }
        __syncthreads();
    }

    // ---- phase 3: expansion r = exp(theta) * W / Y, per-lane over blocks ----
    for (int d = (int)sBeg[t]; d < (int)sEnd[t]; ++d) {
        int   h = stH[d * 64 + t];
        int   e = next_head(stH, sBeg, sEnd, t, d, 64) - 1;
        float c = (float)wsum(h, e) / stY[d * 64 + t];
        for (int j = h; j <= e; ++j) sE[eidx(j)] = __expf(sE[eidx(j)]) * c;
    }
    __syncthreads();
    float* __restrict__ rrow = rs + (size_t)rid * N;
    for (int j = t; j < N; j += 64) rrow[j] = sE[eidx(j)];
}

// ============================================================================
// Kernel 3: correlation via binary search. For each original element, find its
// position in the sorted row (exact key match; ties share a block so any match
// gives the same r) and read its rank. Phase-1 ranks parked in LDS for P.
// ============================================================================
__global__ void __launch_bounds__(NT)
corr_search_kernel(const float* __restrict__ x1, const float* __restrict__ x2,
                   const float* __restrict__ ts, const float* __restrict__ rs,
                   int nrows, float* __restrict__ out)
{
    __shared__ unsigned s_d[N];     // sorted keys (ascending u32)
    __shared__ float    s_r[N];     // r_sorted
    __shared__ float    s_rv[N];    // phase-0 ranks in original order
    __shared__ float    s_red[NT / 64][5];

    const int p   = blockIdx.x;
    const int tid = threadIdx.x;

    float S1 = 0.f, Q1 = 0.f, S2 = 0.f, Q2 = 0.f, P = 0.f;

    for (int phase = 0; phase < 2; ++phase) {
        const int rid = p + phase * nrows;
        const float* __restrict__ trow = ts + (size_t)rid * N;
        const float* __restrict__ rrow = rs + (size_t)rid * N;
        const float* __restrict__ x    = phase ? x2 : x1;
        const size_t base = (size_t)p * N;

        for (int j = tid; j < N; j += NT) {
            s_d[j] = desc_key(trow[j]);
            s_r[j] = rrow[j];
        }
        __syncthreads();

        for (int j = tid; j < N; j += NT) {
            unsigned dv = desc_key(x[base + j] * 10.0f);
            int lo = 0, hi = N - 1;
            #pragma unroll
            for (int it = 0; it < 11; ++it) {
                int mid = (lo + hi) >> 1;
                if (s_d[mid] < dv) lo = mid + 1; else hi = mid;
            }
            float rv = s_r[lo];
            if (phase == 0) {
                s_rv[j] = rv;
                S1 += rv; Q1 += rv * rv;
            } else {
                float a = s_rv[j];
                S2 += rv; Q2 += rv * rv; P += a * rv;
            }
        }
        __syncthreads();
    }

    #pragma unroll
    for (int off = 32; off > 0; off >>= 1) {
        S1 += __shfl_down(S1, off);
        Q1 += __shfl_down(Q1, off);
        S2 += __shfl_down(S2, off);
        Q2 += __shfl_down(Q2, off);
        P  += __shfl_down(P,  off);
    }
    const int wid = tid >> 6, lane = tid & 63;
    if (lane == 0) {
        s_red[wid][0] = S1; s_red[wid][1] = Q1; s_red[wid][2] = S2;
        s_red[wid][3] = Q2; s_red[wid][4] = P;
    }
    __syncthreads();
    if (tid == 0) {
        for (int w = 1; w < NT / 64; ++w) {
            S1 += s_red[w][0]; Q1 += s_red[w][1]; S2 += s_red[w][2];
            Q2 += s_red[w][3]; P  += s_red[w][4];
        }
        const float inv_n = 1.0f / (float)N;
        float num = P  - S1 * S2 * inv_n;
        float d1  = Q1 - S1 * S1 * inv_n;
        float d2  = Q2 - S2 * S2 * inv_n;
        out[p] = 1.0f - num / sqrtf(d1 * d2);
    }
}

// ============================================================================
// Fallback: validated monolithic kernel (used only if ws too small)
// ============================================================================
__global__ void __launch_bounds__(NT)
soft_spearman_mono(const float* __restrict__ x1,
                   const float* __restrict__ x2,
                   float* __restrict__ out)
{
    __shared__ float s_key[N];
    __shared__ int   s_idx[N];
    __shared__ float s_r1[N];
    __shared__ float s_ly[N];
    __shared__ float s_lw[N];
    __shared__ float s_sol[N];
    __shared__ int   s_tgt[N];
    __shared__ int   s_nb;
    __shared__ float s_red[NT / 64][5];

    const int row = blockIdx.x;
    const int tid = threadIdx.x;

    float S1 = 0.f, Q1 = 0.f, S2 = 0.f, Q2 = 0.f, P = 0.f;

    for (int phase = 0; phase < 2; ++phase) {
        const float* __restrict__ x = (phase == 0) ? x1 : x2;
        const size_t base = (size_t)row * N;

        for (int j = tid; j < N; j += NT) {
            s_key[j] = x[base + j] * 10.0f;
            s_idx[j] = j;
        }
        __syncthreads();

        for (int k = 2; k <= N; k <<= 1) {
            for (int jj = k >> 1; jj > 0; jj >>= 1) {
                for (int i = tid; i < N; i += NT) {
                    int l = i ^ jj;
                    if (l > i) {
                        float ki = s_key[i], kl = s_key[l];
                        bool sw = ((i & k) == 0) ? (ki < kl) : (ki > kl);
                        if (sw) {
                            s_key[i] = kl; s_key[l] = ki;
                            int t = s_idx[i]; s_idx[i] = s_idx[l]; s_idx[l] = t;
                        }
                    }
                }
                __syncthreads();
            }
        }

        for (int j = tid; j < N; j += NT) {
            float y = s_key[j];
            float w = logf((float)(N - j));
            s_ly[j]  = y;
            s_lw[j]  = w;
            s_sol[j] = y - w;
            s_tgt[j] = j;
        }
        __syncthreads();

        if (tid == 0) {
            int i = 0;
            while (i < N) {
                int k = s_tgt[i] + 1;
                if (k >= N) break;
                if (s_sol[i] > s_sol[k]) { i = k; continue; }
                float sol_prev = s_sol[i];
                for (;;) {
                    float ly = lae(s_ly[i], s_ly[k]);
                    float lw = lae(s_lw[i], s_lw[k]);
                    s_ly[i] = ly; s_lw[i] = lw; s_sol[i] = ly - lw;
                    int kn = s_tgt[k] + 1;
                    if (kn >= N || sol_prev > s_sol[kn]) {
                        s_tgt[i] = kn - 1;
                        s_tgt[kn - 1] = i;
                        if (i > 0) i = s_tgt[i - 1];
                        break;
                    }
                    k = kn;
                }
            }
            int nb = 0, h = 0;
            while (h < N) {
                int e  = s_tgt[h];
                int hh = h;
                h = e + 1;
                s_tgt[nb++] = hh;
            }
            s_nb = nb;
        }
        __syncthreads();

        const int nb = s_nb;
        for (int j = tid; j < N; j += NT) {
            int lo = 0, hi = nb - 1;
            while (lo < hi) {
                int mid = (lo + hi + 1) >> 1;
                if (s_tgt[mid] <= j) lo = mid; else hi = mid - 1;
            }
            float r = expf(s_key[j] - s_sol[s_tgt[lo]]);
            int   v = s_idx[j];
            if (phase == 0) {
                s_r1[v] = r;
                S1 += r; Q1 += r * r;
            } else {
                float a = s_r1[v];
                S2 += r; Q2 += r * r; P += a * r;
            }
        }
        __syncthreads();
    }

    #pragma unroll
    for (int off = 32; off > 0; off >>= 1) {
        S1 += __shfl_down(S1, off);
        Q1 += __shfl_down(Q1, off);
        S2 += __shfl_down(S2, off);
        Q2 += __shfl_down(Q2, off);
        P  += __shfl_down(P,  off);
    }
    const int wid = tid >> 6, lane = tid & 63;
    if (lane == 0) {
        s_red[wid][0] = S1; s_red[wid][1] = Q1; s_red[wid][2] = S2;
        s_red[wid][3] = Q2; s_red[wid][4] = P;
    }
    __syncthreads();
    if (tid == 0) {
        for (int w = 1; w < NT / 64; ++w) {
            S1 += s_red[w][0]; Q1 += s_red[w][1]; S2 += s_red[w][2];
            Q2 += s_red[w][3]; P  += s_red[w][4];
        }
        const float inv_n = 1.0f / (float)N;
        float num = P  - S1 * S2 * inv_n;
        float d1  = Q1 - S1 * S1 * inv_n;
        float d2  = Q2 - S2 * S2 * inv_n;
        out[row] = 1.0f - num / sqrtf(d1 * d2);
    }
}

extern "C" void kernel_launch(void* const* d_in, const int* in_sizes, int n_in,
                              void* d_out, int out_size, void* d_ws, size_t ws_size,
                              hipStream_t stream) {
    const float* x1 = (const float*)d_in[0];
    const float* x2 = (const float*)d_in[1];
    float* out = (float*)d_out;
    const int nrows = in_sizes[0] / N;        // 4096
    const int total = 2 * nrows;              // 8192 (row,phase) pairs

    // Buffer A: theta_sorted (64 MB).  Buffer B: r_sorted (64 MB).
    const size_t SZ_A = (size_t)total * N * sizeof(float);
    const size_t SZ_B = (size_t)total * N * sizeof(float);
    const size_t need = SZ_A + SZ_B;          // 128 MB

    if (ws_size >= need) {
        float* A = (float*)d_ws;
        float* B = (float*)((char*)d_ws + SZ_A);

        sort_kernel<<<total, NT, 0, stream>>>(x1, x2, nrows, A);
        pav_wave_kernel<<<total, 64, 0, stream>>>(A, B);
        corr_search_kernel<<<nrows, NT, 0, stream>>>(x1, x2, A, B, nrows, out);
    } else {
        soft_spearman_mono<<<nrows, NT, 0, stream>>>(x1, x2, out);
    }
}

// Round 9
// 331.922 us; speedup vs baseline: 1.4337x; 1.4337x over previous
//
#include <hip/hip_runtime.h>
#include <math.h>

#define N   2048
#define NT  256
#define V   8     // elements per thread; N == NT*V

// exact integer block weight: sum_{j=h}^{e} (N-j)  (< 2^22, exact in fp32)
__device__ __forceinline__ int wsum(int h, int e) {
    return (((N - h) + (N - e)) * (e - h + 1)) >> 1;
}

// padded LDS index: +1 word every 32 -> 2-way (free) bank pattern
__device__ __forceinline__ int pidx(int j) { return j + (j >> 5); }

// float -> u32 key; ascending key == descending theta. Exactly invertible.
__device__ __forceinline__ unsigned desc_key(float t) {
    unsigned u = __float_as_uint(t);
    unsigned a = (u & 0x80000000u) ? ~u : (u ^ 0x80000000u);
    return ~a;
}
__device__ __forceinline__ float decode_key(unsigned d) {
    unsigned a = ~d;
    unsigned u = (a & 0x80000000u) ? (a ^ 0x80000000u) : ~a;
    return __uint_as_float(u);
}

// ---- register bitonic helpers (u32, validated R8) --------------------------
__device__ __forceinline__ void ceu(unsigned &a, unsigned &b, bool up) {
    unsigned mn = (a < b) ? a : b;
    unsigned mx = (a < b) ? b : a;
    a = up ? mn : mx;
    b = up ? mx : mn;
}

__device__ __forceinline__ void merge8(unsigned* r, bool up) {
    ceu(r[0], r[4], up); ceu(r[1], r[5], up); ceu(r[2], r[6], up); ceu(r[3], r[7], up);
    ceu(r[0], r[2], up); ceu(r[1], r[3], up); ceu(r[4], r[6], up); ceu(r[5], r[7], up);
    ceu(r[0], r[1], up); ceu(r[2], r[3], up); ceu(r[4], r[5], up); ceu(r[6], r[7], up);
}

__device__ __forceinline__ void shfl_ce(unsigned* r, int d, bool keepMin) {
    #pragma unroll
    for (int q = 0; q < V; ++q) {
        unsigned p = __shfl_xor(r[q], d, 64);
        bool lt = r[q] < p;
        r[q] = (lt == keepMin) ? r[q] : p;
    }
}

// next block head after (lane, d) within lanes [.., bEnd); bEnd*V if none
__device__ __forceinline__ int next_head(const unsigned short* stH,
                                         const unsigned char* sBeg,
                                         const unsigned char* sEnd,
                                         int lane, int d, int bEnd)
{
    if (d + 1 < (int)sEnd[lane]) return stH[(d + 1) * NT + lane];
    for (int l = lane + 1; l < bEnd; ++l)
        if (sBeg[l] != sEnd[l]) return stH[(int)sBeg[l] * NT + l];
    return bEnd << 3;   // bEnd * V
}

// ============================================================================
// Fully fused: one block per (row pair). Per phase (x1 then x2):
//   1. load row, encode u32 keys (kept in registers)
//   2. registerized bitonic sort (3 padded-LDS exchange substages)
//   3. PAV: per-thread stack on its 8 sorted elements (depth<=8, provable:
//      stack entries at a lane always have heads inside its 8-elem segment),
//      then 8-level merge tree resolving only boundary cascades
//   4. expansion r = exp(theta)*W/Y into padded LDS
//   5. binary-search each ORIGINAL element's key (exact bit match; ties share
//      a block => same r) -> rank; accumulate correlation moments in regs
// No intermediate global traffic; only x reads. absmax 0.0 pipeline (R6-R8).
// ============================================================================
__global__ void __launch_bounds__(NT, 4)
fused_kernel(const float* __restrict__ x1, const float* __restrict__ x2,
             float* __restrict__ out)
{
    __shared__ unsigned       s_kx[NT * 9];        // sort exchange / padded keys
    __shared__ float          s_r[N + (N >> 5)];   // padded r_sorted
    __shared__ float          stY[V * NT];         // stack Y  [d][tid]
    __shared__ unsigned short stH[V * NT];         // stack head
    __shared__ unsigned char  sBeg[NT], sEnd[NT];
    __shared__ float          s_red[NT / 64][5];

    const int p   = blockIdx.x;
    const int tid = threadIdx.x;

    float S1 = 0.f, Q1 = 0.f, S2 = 0.f, Q2 = 0.f, P = 0.f;
    float rv1[V];

    for (int ph = 0; ph < 2; ++ph) {
        const float* __restrict__ x = ph ? x2 : x1;
        const size_t base = (size_t)p * N;

        // ---- load + encode (original order kept in keys0) ----
        const float4* __restrict__ xv = (const float4*)(x + base + tid * V);
        float4 a0 = xv[0], a1 = xv[1];
        unsigned keys0[V];
        keys0[0] = desc_key(a0.x * 10.0f); keys0[1] = desc_key(a0.y * 10.0f);
        keys0[2] = desc_key(a0.z * 10.0f); keys0[3] = desc_key(a0.w * 10.0f);
        keys0[4] = desc_key(a1.x * 10.0f); keys0[5] = desc_key(a1.y * 10.0f);
        keys0[6] = desc_key(a1.z * 10.0f); keys0[7] = desc_key(a1.w * 10.0f);
        unsigned r[V];
        #pragma unroll
        for (int q = 0; q < V; ++q) r[q] = keys0[q];

        // ---- bitonic sort: k=2,4 ----
        ceu(r[0], r[1], true);  ceu(r[2], r[3], false);
        ceu(r[4], r[5], true);  ceu(r[6], r[7], false);
        ceu(r[0], r[2], true);  ceu(r[1], r[3], true);
        ceu(r[4], r[6], false); ceu(r[5], r[7], false);
        ceu(r[0], r[1], true);  ceu(r[2], r[3], true);
        ceu(r[4], r[5], false); ceu(r[6], r[7], false);
        merge8(r, (tid & 1) == 0);                       // k=8

        #pragma unroll
        for (int kk = 4; kk <= 11; ++kk) {
            const int k  = 1 << kk;
            const bool up = ((tid & (k >> 3)) == 0);
            #pragma unroll
            for (int jb = kk - 1; jb >= 3; --jb) {
                const int jj = 1 << jb;
                const int d  = jj >> 3;
                if (d >= 64) {
                    __syncthreads();                      // also drains prior-phase readers
                    #pragma unroll
                    for (int q = 0; q < V; ++q) s_kx[tid * 9 + q] = r[q];
                    __syncthreads();
                    const bool keepMin = (up == ((tid & d) == 0));
                    const int ptid = tid ^ d;
                    #pragma unroll
                    for (int q = 0; q < V; ++q) {
                        unsigned pv = s_kx[ptid * 9 + q];
                        bool lt = r[q] < pv;
                        r[q] = (lt == keepMin) ? r[q] : pv;
                    }
                } else {
                    shfl_ce(r, d, up == ((tid & d) == 0));
                }
            }
            merge8(r, up);
        }

        __syncthreads();                 // drain last exchange reads
        #pragma unroll
        for (int q = 0; q < V; ++q) s_kx[pidx(tid * V + q)] = r[q];  // padded keys

        // ---- PAV phase 1: per-thread stack on own 8 sorted elements ----
        {
            int   sp = 0;
            float t0Y = 0.f, t1Y = 0.f;
            int   t0h = 0,   t1h = 0;
            const int bse = tid * V;
            #pragma unroll
            for (int k = 0; k < V; ++k) {
                const int j = bse + k;
                float cY = __expf(decode_key(r[k]));
                int   ch = j;
                while (sp > 0) {
                    float cW = (float)wsum(ch, j);
                    float tW = (float)wsum(t0h, ch - 1);
                    if (t0Y * cW > cY * tW) break;        // strictly decreasing
                    cY += t0Y; ch = t0h;
                    --sp;
                    t0Y = t1Y; t0h = t1h;
                    if (sp > 1) { t1Y = stY[(sp - 2) * NT + tid]; t1h = stH[(sp - 2) * NT + tid]; }
                }
                stY[sp * NT + tid] = cY;
                stH[sp * NT + tid] = (unsigned short)ch;
                t1Y = t0Y; t1h = t0h;
                t0Y = cY;  t0h = ch;
                ++sp;
            }
            sBeg[tid] = 0; sEnd[tid] = (unsigned char)sp;
        }
        __syncthreads();

        // ---- PAV phase 2: merge tree, 8 levels ----
        for (int lev = 0; lev < 8; ++lev) {
            const int g = 1 << lev;
            if ((tid & (2 * g - 1)) == 0) {
                const int a = tid, mid = tid + g, b = tid + 2 * g;
                int l0 = mid - 1;
                while (l0 >= a && sBeg[l0] == sEnd[l0]) --l0;
                int l1 = mid;
                while (l1 < b && sBeg[l1] == sEnd[l1]) ++l1;
                if (l0 >= a && l1 < b) {
                    int   d0  = (int)sEnd[l0] - 1;
                    float tY  = stY[d0 * NT + l0];
                    int   th_ = stH[d0 * NT + l0];
                    int   te  = (mid << 3) - 1;           // G0's last element
                    int   d1  = (int)sBeg[l1];
                    float cY  = stY[d1 * NT + l1];
                    int   ch  = stH[d1 * NT + l1];
                    int   ce  = next_head(stH, sBeg, sEnd, l1, d1, b) - 1;
                    if (!(tY * (float)wsum(ch, ce) > cY * (float)wsum(th_, te))) {
                        sBeg[l1] = (unsigned char)(d1 + 1);   // consume G1 front
                        for (;;) {
                            if (l0 >= a &&
                                !(tY * (float)wsum(ch, ce) > cY * (float)wsum(th_, te))) {
                                // pool left: absorb G0 top [th_, ch-1]
                                cY += tY;
                                ch  = th_;
                                sEnd[l0] = (unsigned char)((int)sEnd[l0] - 1);
                                if (sBeg[l0] == sEnd[l0]) {
                                    do { --l0; } while (l0 >= a && sBeg[l0] == sEnd[l0]);
                                }
                                if (l0 >= a) {
                                    int dd = (int)sEnd[l0] - 1;
                                    tY  = stY[dd * NT + l0];
                                    te  = th_ - 1;
                                    th_ = stH[dd * NT + l0];
                                }
                                continue;
                            }
                            // try pool right: next G1 block
                            while (l1 < b && sBeg[l1] == sEnd[l1]) ++l1;
                            if (l1 < b) {
                                int   dn = (int)sBeg[l1];
                                float nY = stY[dn * NT + l1];
                                int   nh = stH[dn * NT + l1];
                                int   ne = next_head(stH, sBeg, sEnd, l1, dn, b) - 1;
                                if (!(cY * (float)wsum(nh, ne) > nY * (float)wsum(ch, ce))) {
                                    cY += nY; ce = ne;
                                    sBeg[l1] = (unsigned char)(dn + 1);
                                    continue;
                                }
                            }
                            break;
                        }
                        // push merged block at its head's lane
                        int lh = ch >> 3;
                        if (ch >= (mid << 3)) {            // head in G1 -> front push
                            int nb = (int)sBeg[lh] - 1;
                            sBeg[lh] = (unsigned char)nb;
                            stY[nb * NT + lh] = cY;
                            stH[nb * NT + lh] = (unsigned short)ch;
                        } else {                            // head in G0 -> slot of popped entry
                            int nb2 = (int)sEnd[lh];
                            stY[nb2 * NT + lh] = cY;
                            stH[nb2 * NT + lh] = (unsigned short)ch;
                            sEnd[lh] = (unsigned char)(nb2 + 1);
                        }
                    }
                }
            }
            __syncthreads();
        }

        // ---- expansion: r = exp(theta) * W / Y ----
        for (int d = (int)sBeg[tid]; d < (int)sEnd[tid]; ++d) {
            int   h = stH[d * NT + tid];
            int   e = next_head(stH, sBeg, sEnd, tid, d, NT) - 1;
            float c = (float)wsum(h, e) / stY[d * NT + tid];
            for (int j = h; j <= e; ++j)
                s_r[pidx(j)] = __expf(decode_key(s_kx[pidx(j)])) * c;
        }
        __syncthreads();

        // ---- binary search unsort + moment accumulation ----
        #pragma unroll
        for (int q = 0; q < V; ++q) {
            unsigned dv = keys0[q];
            int lo = 0, hi = N - 1;
            #pragma unroll
            for (int it = 0; it < 11; ++it) {
                int mid = (lo + hi) >> 1;
                if (s_kx[pidx(mid)] < dv) lo = mid + 1; else hi = mid;
            }
            float rv = s_r[pidx(lo)];
            if (ph == 0) {
                rv1[q] = rv;
                S1 += rv; Q1 += rv * rv;
            } else {
                S2 += rv; Q2 += rv * rv; P += rv1[q] * rv;
            }
        }
        __syncthreads();   // protect s_kx/s_r before next phase's sort
    }

    // ---- block reduction of the 5 moments ----
    #pragma unroll
    for (int off = 32; off > 0; off >>= 1) {
        S1 += __shfl_down(S1, off);
        Q1 += __shfl_down(Q1, off);
        S2 += __shfl_down(S2, off);
        Q2 += __shfl_down(Q2, off);
        P  += __shfl_down(P,  off);
    }
    const int wid = tid >> 6, lane = tid & 63;
    if (lane == 0) {
        s_red[wid][0] = S1; s_red[wid][1] = Q1; s_red[wid][2] = S2;
        s_red[wid][3] = Q2; s_red[wid][4] = P;
    }
    __syncthreads();
    if (tid == 0) {
        for (int w = 1; w < NT / 64; ++w) {
            S1 += s_red[w][0]; Q1 += s_red[w][1]; S2 += s_red[w][2];
            Q2 += s_red[w][3]; P  += s_red[w][4];
        }
        const float inv_n = 1.0f / (float)N;
        float num = P  - S1 * S2 * inv_n;
        float d1  = Q1 - S1 * S1 * inv_n;
        float d2  = Q2 - S2 * S2 * inv_n;
        out[p] = 1.0f - num / sqrtf(d1 * d2);
    }
}

extern "C" void kernel_launch(void* const* d_in, const int* in_sizes, int n_in,
                              void* d_out, int out_size, void* d_ws, size_t ws_size,
                              hipStream_t stream) {
    const float* x1 = (const float*)d_in[0];
    const float* x2 = (const float*)d_in[1];
    float* out = (float*)d_out;
    const int nrows = in_sizes[0] / N;        // 4096 row pairs
    fused_kernel<<<nrows, NT, 0, stream>>>(x1, x2, out);
}

// Round 10
// 304.904 us; speedup vs baseline: 1.5608x; 1.0886x over previous
//
#include <hip/hip_runtime.h>
#include <math.h>

#define N   2048
#define NT  256
#define V   8     // elements per thread; N == NT*V

// exact integer block weight: sum_{j=h}^{e} (N-j)  (< 2^22, exact in fp32)
__device__ __forceinline__ int wsum(int h, int e) {
    return (((N - h) + (N - e)) * (e - h + 1)) >> 1;
}

// padded LDS index: +1 word every 32 -> conflict-free structured access
__device__ __forceinline__ int pidx(int j) { return j + (j >> 5); }

// float -> u32 key; ascending key == descending theta. Exactly invertible.
__device__ __forceinline__ unsigned desc_key(float t) {
    unsigned u = __float_as_uint(t);
    unsigned a = (u & 0x80000000u) ? ~u : (u ^ 0x80000000u);
    return ~a;
}
__device__ __forceinline__ float decode_key(unsigned d) {
    unsigned a = ~d;
    unsigned u = (a & 0x80000000u) ? (a ^ 0x80000000u) : ~a;
    return __uint_as_float(u);
}

// packed stack entry: Y fp32 (RN to 21-bit mantissa) | 11-bit block head.
// Y>0 finite => bits < 0xFF000000, so 0xFFFFFFFF is a safe sentinel.
#define INVALID_P 0xFFFFFFFFu
__device__ __forceinline__ unsigned packYH(float Y, int h) {
    return ((__float_as_uint(Y) + 0x400u) & 0xFFFFF800u) | (unsigned)h;
}
__device__ __forceinline__ float upY(unsigned u) { return __uint_as_float(u & 0xFFFFF800u); }
__device__ __forceinline__ int   upH(unsigned u) { return (int)(u & 0x7FFu); }

// ---- register bitonic helpers (u32, validated R8/R9) -----------------------
__device__ __forceinline__ void ceu(unsigned &a, unsigned &b, bool up) {
    unsigned mn = (a < b) ? a : b;
    unsigned mx = (a < b) ? b : a;
    a = up ? mn : mx;
    b = up ? mx : mn;
}

__device__ __forceinline__ void merge8(unsigned* r, bool up) {
    ceu(r[0], r[4], up); ceu(r[1], r[5], up); ceu(r[2], r[6], up); ceu(r[3], r[7], up);
    ceu(r[0], r[2], up); ceu(r[1], r[3], up); ceu(r[4], r[6], up); ceu(r[5], r[7], up);
    ceu(r[0], r[1], up); ceu(r[2], r[3], up); ceu(r[4], r[5], up); ceu(r[6], r[7], up);
}

__device__ __forceinline__ void shfl_ce(unsigned* r, int d, bool keepMin) {
    #pragma unroll
    for (int q = 0; q < V; ++q) {
        unsigned p = __shfl_xor(r[q], d, 64);
        bool lt = r[q] < p;
        r[q] = (lt == keepMin) ? r[q] : p;
    }
}

// next block head after (lane, d) within lanes [.., bEnd); bEnd*V if none
__device__ __forceinline__ int next_head_p(const unsigned* sU,
                                           const unsigned char* sBeg,
                                           const unsigned char* sEnd,
                                           int lane, int d, int bEnd)
{
    if (d + 1 < (int)sEnd[lane]) return upH(sU[(d + 1) * NT + lane]);
    for (int l = lane + 1; l < bEnd; ++l)
        if (sBeg[l] != sEnd[l]) return upH(sU[(int)sBeg[l] * NT + l]);
    return bEnd << 3;   // bEnd * V
}

// ============================================================================
// Fully fused, high-occupancy version. One block per row pair; per phase:
//   1. registerized bitonic sort (u32 keys; LDS exchanges in padded layout)
//   2. PAV phase 1: per-thread stack on its 8 sorted elements (packed entries)
//   3. PAV phase 2: 8-level merge tree (boundary cascades only)
//   4. divergence-free expansion: every block lives at lane (head>>3); two
//      log-depth wave scans give each position its governing (h,Y) and its
//      block end; uniform per-thread pass computes r
//   5. binary-search unsort (keys re-derived from a second x load)
// LDS ~17.5 KB (stack array unioned with r array) -> 8 blocks/CU.
// ============================================================================
__global__ void __launch_bounds__(NT, 8)
fused_kernel(const float* __restrict__ x1, const float* __restrict__ x2,
             float* __restrict__ out)
{
    __shared__ unsigned      s_kx[N + (N >> 5)];   // 8448 B: sort exchange + sorted keys
    __shared__ unsigned      s_u [N + (N >> 5)];   // 8448 B: stacks -> packed(h,Y) -> r
    __shared__ unsigned char sBeg[NT], sEnd[NT];
    __shared__ float         s_red[NT / 64][5];
    __shared__ unsigned      swF[NT / 64];
    __shared__ int           swB[NT / 64];

    float* s_rf = (float*)s_u;

    const int p    = blockIdx.x;
    const int tid  = threadIdx.x;
    const int lane = tid & 63;
    const int wid  = tid >> 6;

    float S1 = 0.f, Q1 = 0.f, S2 = 0.f, Q2 = 0.f, P = 0.f;
    float rv1[V];

    for (int ph = 0; ph < 2; ++ph) {
        const float* __restrict__ x = ph ? x2 : x1;
        const size_t base = (size_t)p * N;

        // ---- load + encode ----
        const float4* __restrict__ xv = (const float4*)(x + base + tid * V);
        float4 a0 = xv[0], a1 = xv[1];
        unsigned r[V];
        r[0] = desc_key(a0.x * 10.0f); r[1] = desc_key(a0.y * 10.0f);
        r[2] = desc_key(a0.z * 10.0f); r[3] = desc_key(a0.w * 10.0f);
        r[4] = desc_key(a1.x * 10.0f); r[5] = desc_key(a1.y * 10.0f);
        r[6] = desc_key(a1.z * 10.0f); r[7] = desc_key(a1.w * 10.0f);

        // ---- bitonic sort: k=2,4,8 ----
        ceu(r[0], r[1], true);  ceu(r[2], r[3], false);
        ceu(r[4], r[5], true);  ceu(r[6], r[7], false);
        ceu(r[0], r[2], true);  ceu(r[1], r[3], true);
        ceu(r[4], r[6], false); ceu(r[5], r[7], false);
        ceu(r[0], r[1], true);  ceu(r[2], r[3], true);
        ceu(r[4], r[5], false); ceu(r[6], r[7], false);
        merge8(r, (tid & 1) == 0);

        #pragma unroll
        for (int kk = 4; kk <= 11; ++kk) {
            const int k  = 1 << kk;
            const bool up = ((tid & (k >> 3)) == 0);
            #pragma unroll
            for (int jb = kk - 1; jb >= 3; --jb) {
                const int jj = 1 << jb;
                const int d  = jj >> 3;
                if (d >= 64) {
                    __syncthreads();
                    #pragma unroll
                    for (int q = 0; q < V; ++q) s_kx[pidx(tid * V + q)] = r[q];
                    __syncthreads();
                    const bool keepMin = (up == ((tid & d) == 0));
                    const int ptid = tid ^ d;
                    #pragma unroll
                    for (int q = 0; q < V; ++q) {
                        unsigned pv = s_kx[pidx(ptid * V + q)];
                        bool lt = r[q] < pv;
                        r[q] = (lt == keepMin) ? r[q] : pv;
                    }
                } else {
                    shfl_ce(r, d, up == ((tid & d) == 0));
                }
            }
            merge8(r, up);
        }

        __syncthreads();                  // drain last exchange readers
        #pragma unroll
        for (int q = 0; q < V; ++q) s_kx[pidx(tid * V + q)] = r[q];

        // ---- PAV phase 1: per-thread stack (packed entries in s_u) ----
        {
            int   sp = 0;
            float t0Y = 0.f, t1Y = 0.f;
            int   t0h = 0,   t1h = 0;
            const int bse = tid * V;
            #pragma unroll
            for (int k = 0; k < V; ++k) {
                const int j = bse + k;
                float cY = __expf(decode_key(r[k]));
                int   ch = j;
                while (sp > 0) {
                    float cW = (float)wsum(ch, j);
                    float tW = (float)wsum(t0h, ch - 1);
                    if (t0Y * cW > cY * tW) break;        // strictly decreasing
                    cY += t0Y; ch = t0h;
                    --sp;
                    t0Y = t1Y; t0h = t1h;
                    if (sp > 1) {
                        unsigned u = s_u[(sp - 2) * NT + tid];
                        t1Y = upY(u); t1h = upH(u);
                    }
                }
                s_u[sp * NT + tid] = packYH(cY, ch);
                t1Y = t0Y; t1h = t0h;
                t0Y = cY;  t0h = ch;
                ++sp;
            }
            sBeg[tid] = 0; sEnd[tid] = (unsigned char)sp;
        }
        __syncthreads();

        // ---- PAV phase 2: merge tree, 8 levels ----
        for (int lev = 0; lev < 8; ++lev) {
            const int g = 1 << lev;
            if ((tid & (2 * g - 1)) == 0) {
                const int a = tid, mid = tid + g, b = tid + 2 * g;
                int l0 = mid - 1;
                while (l0 >= a && sBeg[l0] == sEnd[l0]) --l0;
                int l1 = mid;
                while (l1 < b && sBeg[l1] == sEnd[l1]) ++l1;
                if (l0 >= a && l1 < b) {
                    int d0 = (int)sEnd[l0] - 1;
                    unsigned tu = s_u[d0 * NT + l0];
                    float tY = upY(tu); int th_ = upH(tu);
                    int te = (mid << 3) - 1;
                    int d1 = (int)sBeg[l1];
                    unsigned cu = s_u[d1 * NT + l1];
                    float cY = upY(cu); int ch = upH(cu);
                    int ce = next_head_p(s_u, sBeg, sEnd, l1, d1, b) - 1;
                    if (!(tY * (float)wsum(ch, ce) > cY * (float)wsum(th_, te))) {
                        sBeg[l1] = (unsigned char)(d1 + 1);   // consume G1 front
                        for (;;) {
                            if (l0 >= a &&
                                !(tY * (float)wsum(ch, ce) > cY * (float)wsum(th_, te))) {
                                cY += tY; ch = th_;           // absorb G0 top
                                sEnd[l0] = (unsigned char)((int)sEnd[l0] - 1);
                                if (sBeg[l0] == sEnd[l0]) {
                                    do { --l0; } while (l0 >= a && sBeg[l0] == sEnd[l0]);
                                }
                                if (l0 >= a) {
                                    int dd = (int)sEnd[l0] - 1;
                                    unsigned uu = s_u[dd * NT + l0];
                                    tY = upY(uu); te = th_ - 1; th_ = upH(uu);
                                }
                                continue;
                            }
                            while (l1 < b && sBeg[l1] == sEnd[l1]) ++l1;
                            if (l1 < b) {                      // absorb next G1 block?
                                int dn = (int)sBeg[l1];
                                unsigned nu = s_u[dn * NT + l1];
                                float nY = upY(nu); int nh = upH(nu);
                                int ne = next_head_p(s_u, sBeg, sEnd, l1, dn, b) - 1;
                                if (!(cY * (float)wsum(nh, ne) > nY * (float)wsum(ch, ce))) {
                                    cY += nY; ce = ne;
                                    sBeg[l1] = (unsigned char)(dn + 1);
                                    continue;
                                }
                            }
                            break;
                        }
                        int lh = ch >> 3;                      // push at head's lane
                        if (ch >= (mid << 3)) {                // head in G1 -> front
                            int nb = (int)sBeg[lh] - 1;
                            sBeg[lh] = (unsigned char)nb;
                            s_u[nb * NT + lh] = packYH(cY, ch);
                        } else {                               // head in G0 -> tail
                            int nb2 = (int)sEnd[lh];
                            s_u[nb2 * NT + lh] = packYH(cY, ch);
                            sEnd[lh] = (unsigned char)(nb2 + 1);
                        }
                    }
                }
            }
            __syncthreads();
        }

        // ---- divergence-free expansion ----
        const int b0 = sBeg[tid], b1 = sEnd[tid];
        unsigned stReg[V];
        #pragma unroll
        for (int d = 0; d < V; ++d) stReg[d] = s_u[d * NT + tid];
        unsigned myLast  = (b1 > b0) ? stReg[b1 - 1] : INVALID_P;
        int      myFirst = (b1 > b0) ? upH(stReg[b0]) : N;

        // forward wave scan: rightmost valid packed entry among lanes <= lane
        unsigned fv = myLast;
        #pragma unroll
        for (int off = 1; off < 64; off <<= 1) {
            unsigned o = (unsigned)__shfl_up((int)fv, off);
            if (fv == INVALID_P) fv = o;
        }
        unsigned cF = (unsigned)__shfl_up((int)fv, 1);
        if (lane == 0) cF = INVALID_P;
        // backward wave scan: leftmost head among lanes >= lane
        int bv = myFirst;
        #pragma unroll
        for (int off = 1; off < 64; off <<= 1) {
            int o = __shfl_down(bv, off);
            if (bv == N) bv = o;
        }
        int cB = __shfl_down(bv, 1);
        if (lane == 63) cB = N;
        if (lane == 63) swF[wid] = fv;
        if (lane == 0)  swB[wid] = bv;
        __syncthreads();    // also guarantees all stReg pre-loads are done
        if (cF == INVALID_P)
            for (int w = wid - 1; w >= 0; --w)
                if (swF[w] != INVALID_P) { cF = swF[w]; break; }
        if (cB == N)
            for (int w = wid + 1; w < NT / 64; ++w)
                if (swB[w] != N) { cB = swB[w]; break; }

        // fwd pass: per position, governing packed (h,Y) -> s_u
        {
            int dptr = b0;
            int nxtOwn = (dptr < b1) ? upH(stReg[dptr]) : N;
            unsigned cur = cF;
            #pragma unroll
            for (int q = 0; q < V; ++q) {
                int j = tid * V + q;
                if (j == nxtOwn) {
                    cur = stReg[dptr];
                    ++dptr;
                    nxtOwn = (dptr < b1) ? upH(stReg[dptr]) : N;
                }
                s_u[pidx(j)] = cur;
            }
        }
        // bwd pass: per position, block end e -> r = exp(theta)*W/Y (in place)
        {
            int dptr2 = b1 - 1;
            int nxt = cB;
            #pragma unroll
            for (int q = V - 1; q >= 0; --q) {
                int j = tid * V + q;
                int e = nxt - 1;
                unsigned cu = s_u[pidx(j)];
                float c  = (float)wsum(upH(cu), e) / upY(cu);
                float rv = __expf(decode_key(r[q])) * c;
                s_rf[pidx(j)] = rv;
                if (dptr2 >= b0 && upH(stReg[dptr2]) == j) { nxt = j; --dptr2; }
            }
        }
        __syncthreads();

        // ---- binary-search unsort + moments (keys re-derived from x) ----
        {
            float4 c0 = xv[0], c1 = xv[1];
            float xx[V] = {c0.x, c0.y, c0.z, c0.w, c1.x, c1.y, c1.z, c1.w};
            #pragma unroll
            for (int q = 0; q < V; ++q) {
                unsigned dv = desc_key(xx[q] * 10.0f);
                int lo = 0, hi = N - 1;
                #pragma unroll
                for (int it = 0; it < 11; ++it) {
                    int mid = (lo + hi) >> 1;
                    if (s_kx[pidx(mid)] < dv) lo = mid + 1; else hi = mid;
                }
                float rv = s_rf[pidx(lo)];
                if (ph == 0) {
                    rv1[q] = rv;
                    S1 += rv; Q1 += rv * rv;
                } else {
                    S2 += rv; Q2 += rv * rv; P += rv1[q] * rv;
                }
            }
        }
        __syncthreads();   // protect s_kx/s_u before next phase
    }

    // ---- block reduction of the 5 moments ----
    #pragma unroll
    for (int off = 32; off > 0; off >>= 1) {
        S1 += __shfl_down(S1, off);
        Q1 += __shfl_down(Q1, off);
        S2 += __shfl_down(S2, off);
        Q2 += __shfl_down(Q2, off);
        P  += __shfl_down(P,  off);
    }
    if (lane == 0) {
        s_red[wid][0] = S1; s_red[wid][1] = Q1; s_red[wid][2] = S2;
        s_red[wid][3] = Q2; s_red[wid][4] = P;
    }
    __syncthreads();
    if (tid == 0) {
        for (int w = 1; w < NT / 64; ++w) {
            S1 += s_red[w][0]; Q1 += s_red[w][1]; S2 += s_red[w][2];
            Q2 += s_red[w][3]; P  += s_red[w][4];
        }
        const float inv_n = 1.0f / (float)N;
        float num = P  - S1 * S2 * inv_n;
        float d1  = Q1 - S1 * S1 * inv_n;
        float d2  = Q2 - S2 * S2 * inv_n;
        out[p] = 1.0f - num / sqrtf(d1 * d2);
    }
}

extern "C" void kernel_launch(void* const* d_in, const int* in_sizes, int n_in,
                              void* d_out, int out_size, void* d_ws, size_t ws_size,
                              hipStream_t stream) {
    const float* x1 = (const float*)d_in[0];
    const float* x2 = (const float*)d_in[1];
    float* out = (float*)d_out;
    const int nrows = in_sizes[0] / N;        // 4096 row pairs
    fused_kernel<<<nrows, NT, 0, stream>>>(x1, x2, out);
}